// Round 13
// baseline (126.776 us; speedup 1.0000x reference)
//
#include <hip/hip_runtime.h>
#include <stdint.h>

#define NPIX 3136      // 56*56
#define OC 256
#define IC 256
#define CPF 32
#define XH_BYTES 6422528   // 3,211,264 halfs

typedef _Float16 h2_t __attribute__((ext_vector_type(2)));

__device__ __forceinline__ uint32_t pk16(float lo, float hi) {
    uint16_t l = __builtin_bit_cast(uint16_t, (_Float16)lo);
    uint16_t h = __builtin_bit_cast(uint16_t, (_Float16)hi);
    return (uint32_t)l | ((uint32_t)h << 16);
}
__device__ __forceinline__ float fdot2(uint32_t w, uint32_t xp, float acc) {
    return __builtin_amdgcn_fdot2(__builtin_bit_cast(h2_t, w),
                                  __builtin_bit_cast(h2_t, xp), acc, false);
}
// lane s gets lane s-1's value within 16-lane DPP row; s%16==0 -> 0
__device__ __forceinline__ uint32_t dpp_shr1(uint32_t v) {
    return (uint32_t)__builtin_amdgcn_update_dpp(0, (int)v, 0x111, 0xF, 0xF, true);
}
// lane s gets lane s+1's value within 16-lane DPP row; s%16==15 -> 0
__device__ __forceinline__ uint32_t dpp_shl1(uint32_t v) {
    return (uint32_t)__builtin_amdgcn_update_dpp(0, (int)v, 0x101, 0xF, 0xF, true);
}

// Pass 1: x fp32 -> fp16 (8 floats/thread; 1568*256*8 = 3,211,264 exactly).
__global__ __launch_bounds__(256) void cvt_x(const float* __restrict__ x,
                                             uint32_t* __restrict__ xh) {
    const int i = blockIdx.x * 256 + threadIdx.x;
    const float4 a = ((const float4*)x)[2 * i];
    const float4 b = ((const float4*)x)[2 * i + 1];
    uint4 o;
    o.x = pk16(a.x, a.y); o.y = pk16(a.z, a.w);
    o.z = pk16(b.x, b.y); o.w = pk16(b.z, b.w);
    ((uint4*)xh)[i] = o;
}

// Pass 2: weight fp32 -> channel-pair-packed fp16: wp[o][cc][kd] = (w[2cc],w[2cc+1]).
__global__ __launch_bounds__(256) void cvt_w(const float* __restrict__ w,
                                             uint32_t* __restrict__ wp) {
    const int i = blockIdx.x * 256 + threadIdx.x;
    const int o = i / 144, rem = i - o * 144;
    const int cc = rem / 9, kd = rem - cc * 9;
    const float w0 = w[(o * CPF + 2 * cc) * 9 + kd];
    const float w1 = w[(o * CPF + 2 * cc + 1) * 9 + kd];
    wp[i] = pk16(w0, w1);
}

// Main: one block per (b, o, half-plane) -> grid 2048 = 8 blocks/CU = 32
// waves/CU for latency hiding (no LDS, no barriers; x fp16 L2-resident).
// Thread (g=t>>4, s=t&15) computes a 2x4 fp32 tile via v_dot2_f32_f16 on
// packed channel pairs. Column halos via DPP; row halos via clamped addr +
// exec-mask. 2-deep register pipeline over the 16 channel-pairs.
__global__ __launch_bounds__(256, 8) void sparse_conv_kernel(
    const uint16_t* __restrict__ xh, const uint32_t* __restrict__ wp,
    const int* __restrict__ connections, float* __restrict__ out)
{
    const int bid  = blockIdx.x;
    const int half = bid & 1;          // bid%8 = (b,half): per-XCD set ~0.9 MB
    const int b    = (bid >> 1) & 3;
    const int o    = bid >> 3;
    const int t = threadIdx.x;
    const int s = t & 15;
    const int g = t >> 4;
    const bool active = (g < 14);
    const bool redge = (s == 13);
    const int r0 = half * 28;          // first output row of this block

    const uint32_t* wo = wp + o * 144;

    // Hoist connections once (uniform -> SGPRs).
    int cn[CPF];
#pragma unroll
    for (int i = 0; i < CPF; ++i) cn[i] = connections[o * CPF + i];

    // Row offsets (rows AND cols clamped -> never OOB) + validity masks.
    int off[4]; bool mk[4];
    const int col = (4 * s > 52) ? 52 : 4 * s;   // s>=14 lanes clamped
#pragma unroll
    for (int k = 0; k < 4; ++k) {
        const int rr = r0 + 2 * g - 1 + k;
        const int rc = rr < 0 ? 0 : (rr > 55 ? 55 : rr);
        off[k] = rc * 56 + col;
        mk[k] = ((unsigned)rr < 56u) && active;
    }

    float4 acc[2];
    acc[0] = make_float4(0.f, 0.f, 0.f, 0.f);
    acc[1] = make_float4(0.f, 0.f, 0.f, 0.f);

    auto loadpair = [&](int cc, uint2* A, uint2* B) {
        const uint16_t* p0 = xh + ((size_t)b * IC + cn[2 * cc]) * NPIX;
        const uint16_t* p1 = xh + ((size_t)b * IC + cn[2 * cc + 1]) * NPIX;
#pragma unroll
        for (int k = 0; k < 4; ++k) {
            A[k] = *reinterpret_cast<const uint2*>(p0 + off[k]);
            B[k] = *reinterpret_cast<const uint2*>(p1 + off[k]);
        }
    };

    auto compute = [&](const uint2* A, const uint2* B, int cc) {
        uint32_t wt[9];
        const uint32_t* w9 = wo + cc * 9;
#pragma unroll
        for (int i = 0; i < 9; ++i) wt[i] = w9[i];   // uniform -> s_load
#pragma unroll
        for (int k = 0; k < 4; ++k) {
            if (mk[k]) {                             // exec-mask (SALU)
                const uint32_t I0 = __builtin_amdgcn_perm(A[k].x, B[k].x, 0x01000504u);
                const uint32_t I1 = __builtin_amdgcn_perm(A[k].x, B[k].x, 0x03020706u);
                const uint32_t I2 = __builtin_amdgcn_perm(A[k].y, B[k].y, 0x01000504u);
                const uint32_t I3 = __builtin_amdgcn_perm(A[k].y, B[k].y, 0x03020706u);
                const uint32_t Lp = dpp_shr1(I3);    // col 4s-1 pair
                uint32_t       Rp = dpp_shl1(I0);    // col 4s+4 pair
                Rp = redge ? 0u : Rp;
#pragma unroll
                for (int r = 0; r < 2; ++r) {
                    const int kh = k - r;
                    if (kh >= 0 && kh < 3) {
                        const uint32_t w0 = wt[kh * 3 + 0];
                        const uint32_t w1 = wt[kh * 3 + 1];
                        const uint32_t w2 = wt[kh * 3 + 2];
                        acc[r].x = fdot2(w2, I1, fdot2(w1, I0, fdot2(w0, Lp, acc[r].x)));
                        acc[r].y = fdot2(w2, I2, fdot2(w1, I1, fdot2(w0, I0, acc[r].y)));
                        acc[r].z = fdot2(w2, I3, fdot2(w1, I2, fdot2(w0, I1, acc[r].z)));
                        acc[r].w = fdot2(w2, Rp, fdot2(w1, I3, fdot2(w0, I2, acc[r].w)));
                    }
                }
            }
        }
    };

    // 2-deep software pipeline over the 16 channel-pairs.
    uint2 A0[4], B0[4], A1[4], B1[4];
    loadpair(0, A0, B0);
#pragma unroll 1
    for (int it = 0; it < 8; ++it) {
        const int cc = 2 * it;
        loadpair(cc + 1, A1, B1);
        compute(A0, B0, cc);
        if (it < 7) loadpair(cc + 2, A0, B0);
        compute(A1, B1, cc + 1);
    }

    if (active && s < 14) {
        float* ob = out + ((size_t)b * OC + o) * NPIX + (r0 + 2 * g) * 56 + 4 * s;
        *reinterpret_cast<float4*>(ob)      = acc[0];
        *reinterpret_cast<float4*>(ob + 56) = acc[1];
    }
}

extern "C" void kernel_launch(void* const* d_in, const int* in_sizes, int n_in,
                              void* d_out, int out_size, void* d_ws, size_t ws_size,
                              hipStream_t stream) {
    const float* x    = (const float*)d_in[0];
    const float* wgt  = (const float*)d_in[1];
    const int*   conn = (const int*)d_in[2];
    float* out = (float*)d_out;

    uint32_t* xh = (uint32_t*)d_ws;                          // 6,422,528 B
    uint32_t* wp = (uint32_t*)((char*)d_ws + XH_BYTES);      // +147,456 B

    hipLaunchKernelGGL(cvt_x, dim3(1568), dim3(256), 0, stream, x, xh);
    hipLaunchKernelGGL(cvt_w, dim3(144),  dim3(256), 0, stream, wgt, wp);
    hipLaunchKernelGGL(sparse_conv_kernel, dim3(2048), dim3(256), 0, stream,
                       (const uint16_t*)xh, wp, conn, out);
}

// Round 15
// 104.566 us; speedup vs baseline: 1.2124x; 1.2124x over previous
//
#include <hip/hip_runtime.h>
#include <stdint.h>

#define NPIX 3136      // 56*56
#define OC 256
#define IC 256
#define CPF 32
#define XH_BYTES 6422528   // 3,211,264 halfs

typedef _Float16 h2_t __attribute__((ext_vector_type(2)));

__device__ __forceinline__ uint32_t pk16(float lo, float hi) {
    uint16_t l = __builtin_bit_cast(uint16_t, (_Float16)lo);
    uint16_t h = __builtin_bit_cast(uint16_t, (_Float16)hi);
    return (uint32_t)l | ((uint32_t)h << 16);
}
__device__ __forceinline__ float fdot2(uint32_t w, uint32_t xp, float acc) {
    return __builtin_amdgcn_fdot2(__builtin_bit_cast(h2_t, w),
                                  __builtin_bit_cast(h2_t, xp), acc, false);
}
// lane s gets lane s-1's value within 16-lane DPP row; s%16==0 -> 0
__device__ __forceinline__ uint32_t dpp_shr1(uint32_t v) {
    return (uint32_t)__builtin_amdgcn_update_dpp(0, (int)v, 0x111, 0xF, 0xF, true);
}
// lane s gets lane s+1's value within 16-lane DPP row; s%16==15 -> 0
__device__ __forceinline__ uint32_t dpp_shl1(uint32_t v) {
    return (uint32_t)__builtin_amdgcn_update_dpp(0, (int)v, 0x101, 0xF, 0xF, true);
}

// Pass 1: x fp32 -> fp16 (8 floats/thread; 1568*256*8 = 3,211,264 exactly).
__global__ __launch_bounds__(256) void cvt_x(const float* __restrict__ x,
                                             uint32_t* __restrict__ xh) {
    const int i = blockIdx.x * 256 + threadIdx.x;
    const float4 a = ((const float4*)x)[2 * i];
    const float4 b = ((const float4*)x)[2 * i + 1];
    uint4 o;
    o.x = pk16(a.x, a.y); o.y = pk16(a.z, a.w);
    o.z = pk16(b.x, b.y); o.w = pk16(b.z, b.w);
    ((uint4*)xh)[i] = o;
}

// Pass 2: weight fp32 -> channel-pair-packed fp16: wp[o][cc][kd] = (w[2cc],w[2cc+1]).
__global__ __launch_bounds__(256) void cvt_w(const float* __restrict__ w,
                                             uint32_t* __restrict__ wp) {
    const int i = blockIdx.x * 256 + threadIdx.x;
    const int o = i / 144, rem = i - o * 144;
    const int cc = rem / 9, kd = rem - cc * 9;
    const float w0 = w[(o * CPF + 2 * cc) * 9 + kd];
    const float w1 = w[(o * CPF + 2 * cc + 1) * 9 + kd];
    wp[i] = pk16(w0, w1);
}

// Main: one block per (b, o, half-plane) -> grid 2048. launch_bounds(256,6)
// guarantees >=6 blocks/CU WITHOUT starving the allocator (R13's (256,8)
// forced VGPR=32 -> 65 MB of spills). Expected ~55-60 VGPR -> 8 blocks/CU.
// No LDS, no barriers; x fp16 L2-resident. Thread (g=t>>4, s=t&15) computes
// a 2x4 fp32 tile via v_dot2_f32_f16 on packed channel pairs. Column halos
// via DPP; row halos via clamped addr + exec-mask. 2-deep register pipeline.
__global__ __launch_bounds__(256, 6) void sparse_conv_kernel(
    const uint16_t* __restrict__ xh, const uint32_t* __restrict__ wp,
    const int* __restrict__ connections, float* __restrict__ out)
{
    const int bid  = blockIdx.x;
    const int half = bid & 1;          // bid%8 = (b,half): per-XCD set ~0.9 MB
    const int b    = (bid >> 1) & 3;
    const int o    = bid >> 3;
    const int t = threadIdx.x;
    const int s = t & 15;
    const int g = t >> 4;
    const bool active = (g < 14);
    const bool redge = (s == 13);
    const int r0 = half * 28;          // first output row of this block

    const int*      conn = connections + o * CPF;   // uniform -> s_load
    const uint32_t* wo   = wp + o * 144;

    // Row offsets (rows AND cols clamped -> never OOB) + validity masks.
    int off[4]; bool mk[4];
    const int col = (4 * s > 52) ? 52 : 4 * s;   // s>=14 lanes clamped
#pragma unroll
    for (int k = 0; k < 4; ++k) {
        const int rr = r0 + 2 * g - 1 + k;
        const int rc = rr < 0 ? 0 : (rr > 55 ? 55 : rr);
        off[k] = rc * 56 + col;
        mk[k] = ((unsigned)rr < 56u) && active;
    }

    float4 acc[2];
    acc[0] = make_float4(0.f, 0.f, 0.f, 0.f);
    acc[1] = make_float4(0.f, 0.f, 0.f, 0.f);

    auto loadpair = [&](int cc, uint2* A, uint2* B) {
        const uint16_t* p0 = xh + ((size_t)b * IC + conn[2 * cc]) * NPIX;
        const uint16_t* p1 = xh + ((size_t)b * IC + conn[2 * cc + 1]) * NPIX;
#pragma unroll
        for (int k = 0; k < 4; ++k) {
            A[k] = *reinterpret_cast<const uint2*>(p0 + off[k]);
            B[k] = *reinterpret_cast<const uint2*>(p1 + off[k]);
        }
    };

    auto compute = [&](const uint2* A, const uint2* B, int cc) {
        uint32_t wt[9];
        const uint32_t* w9 = wo + cc * 9;
#pragma unroll
        for (int i = 0; i < 9; ++i) wt[i] = w9[i];   // uniform -> s_load
#pragma unroll
        for (int k = 0; k < 4; ++k) {
            if (mk[k]) {                             // exec-mask (SALU)
                const uint32_t I0 = __builtin_amdgcn_perm(A[k].x, B[k].x, 0x01000504u);
                const uint32_t I1 = __builtin_amdgcn_perm(A[k].x, B[k].x, 0x03020706u);
                const uint32_t I2 = __builtin_amdgcn_perm(A[k].y, B[k].y, 0x01000504u);
                const uint32_t I3 = __builtin_amdgcn_perm(A[k].y, B[k].y, 0x03020706u);
                const uint32_t Lp = dpp_shr1(I3);    // col 4s-1 pair
                uint32_t       Rp = dpp_shl1(I0);    // col 4s+4 pair
                Rp = redge ? 0u : Rp;
#pragma unroll
                for (int r = 0; r < 2; ++r) {
                    const int kh = k - r;
                    if (kh >= 0 && kh < 3) {
                        const uint32_t w0 = wt[kh * 3 + 0];
                        const uint32_t w1 = wt[kh * 3 + 1];
                        const uint32_t w2 = wt[kh * 3 + 2];
                        acc[r].x = fdot2(w2, I1, fdot2(w1, I0, fdot2(w0, Lp, acc[r].x)));
                        acc[r].y = fdot2(w2, I2, fdot2(w1, I1, fdot2(w0, I0, acc[r].y)));
                        acc[r].z = fdot2(w2, I3, fdot2(w1, I2, fdot2(w0, I1, acc[r].z)));
                        acc[r].w = fdot2(w2, Rp, fdot2(w1, I3, fdot2(w0, I2, acc[r].w)));
                    }
                }
            }
        }
    };

    // 2-deep software pipeline over the 16 channel-pairs.
    uint2 A0[4], B0[4], A1[4], B1[4];
    loadpair(0, A0, B0);
#pragma unroll 1
    for (int it = 0; it < 8; ++it) {
        const int cc = 2 * it;
        loadpair(cc + 1, A1, B1);
        compute(A0, B0, cc);
        if (it < 7) loadpair(cc + 2, A0, B0);
        compute(A1, B1, cc + 1);
    }

    if (active && s < 14) {
        float* ob = out + ((size_t)b * OC + o) * NPIX + (r0 + 2 * g) * 56 + 4 * s;
        *reinterpret_cast<float4*>(ob)      = acc[0];
        *reinterpret_cast<float4*>(ob + 56) = acc[1];
    }
}

extern "C" void kernel_launch(void* const* d_in, const int* in_sizes, int n_in,
                              void* d_out, int out_size, void* d_ws, size_t ws_size,
                              hipStream_t stream) {
    const float* x    = (const float*)d_in[0];
    const float* wgt  = (const float*)d_in[1];
    const int*   conn = (const int*)d_in[2];
    float* out = (float*)d_out;

    uint32_t* xh = (uint32_t*)d_ws;                          // 6,422,528 B
    uint32_t* wp = (uint32_t*)((char*)d_ws + XH_BYTES);      // +147,456 B

    hipLaunchKernelGGL(cvt_x, dim3(1568), dim3(256), 0, stream, x, xh);
    hipLaunchKernelGGL(cvt_w, dim3(144),  dim3(256), 0, stream, wgt, wp);
    hipLaunchKernelGGL(sparse_conv_kernel, dim3(2048), dim3(256), 0, stream,
                       (const uint16_t*)xh, wp, conn, out);
}